// Round 9
// baseline (443.377 us; speedup 1.0000x reference)
//
#include <hip/hip_runtime.h>
#include <hip/hip_bf16.h>
#include <stdint.h>
#include <stddef.h>

#define N_NODES 200000
#define N_EDGES 800000
#define NREL 16
#define NBASES 8

typedef __attribute__((ext_vector_type(8))) short short8b;
typedef __attribute__((ext_vector_type(4))) float float4v;
typedef __attribute__((ext_vector_type(4))) int int4v;

__device__ __forceinline__ short f32_bf16(float f) {
  uint32_t u = __builtin_bit_cast(uint32_t, f);
  uint32_t r = u + 0x7FFFu + ((u >> 16) & 1u);
  return (short)(uint16_t)(r >> 16);
}
// hardware RNE conversion (gfx950); same rounding as the manual version
__device__ __forceinline__ uint16_t f32_bf16_hw(float f) {
  __hip_bfloat16 h = __float2bfloat16(f);
  return __builtin_bit_cast(uint16_t, h);
}
__device__ __forceinline__ float bf2f(uint16_t h) {
  return __builtin_bit_cast(float, (uint32_t)h << 16);
}

// ======================================================================
// MAIN PATH (v9): g-formulation, NO message materialization.
//   out[t] = (Σ_{e->t} att[r_e]⊗x_{s_e}) · Bstack   (K=512 MFMA)
// Pipeline:
//   k_init   : Bstack^T bf16 (Bt[e][k], k=b*64+d) + zero control head
//   k_count  : per-1024-edge-block bucket histograms H  (+ x->bf16 cast)
//   k_base   : column scan of H -> per-(block,bucket) scatter bases
//   k_scat   : scatter packed endpoint items into bucket regions
//   k_slot   : per-bucket LDS counters + segment scan -> eslot (ABSOLUTE
//              slots), vstart/cntt, self rec2=(v,NREL)
//   k_write  : rec2[slot] = (srcnode, rel)  (8-B records, 2/edge)
//   k_phaseAB: per 16-target tile: VALU-accumulate g (4 waves x 4 targets,
//              lane=dim), LDS transpose, K=512 MFMA vs Bt, write out f32
// ======================================================================
#define NB 196                 // node buckets of 1024 (196*1024 >= 200000)
#define CNT_BLOCKS  782        // ceil(800000/1024) edge blocks
#define CAST_BLOCKS 6250
#define MAXSLOTS (2 * N_EDGES + N_NODES)   // 1.8M

// workspace layout (all offsets 16-B aligned where needed)
#define WS_GCUR2   128        // 1 int (bucket-region allocator)
#define WS_GCUR    384        // 1 int (segment allocator)
#define WS_BT      512        // 64*512 u16 = 65536 -> ends 66048
#define WS_VSTART  66560      // 200000 int
#define WS_CNTT    866560     // 200000 int
#define WS_ESLOT   1666560    // 2E int = 6.4 MB
#define WS_SCRATCH 8066560    // 2E int = 6.4 MB
#define WS_H       14466560   // 782*196 int
#define WS_BASEM   15079648   // 782*196 int
#define WS_REGS    15692736   // 2*196 int
#define WS_REC2    15694336   // MAXSLOTS int2 = 14.4 MB
#define WS_XB      30094336   // 200000*64 u16 = 25.6 MB -> ends 55.7 MB
// gate: keep the old (round-8) threshold, known to pass on this harness
#define WS_GATE    (17056128 + (size_t)112528 * 16 * 128)

// Fused: Bt prep (blocks 0..127) | zero control head (block 128)
__global__ __launch_bounds__(256) void k_init(const float* __restrict__ bases,
                                              uint16_t* __restrict__ Bt,
                                              int* __restrict__ zero0) {
  int b = blockIdx.x;
  int tid = threadIdx.x;
  if (b < 128) {
    int i = b * 256 + tid;              // i < 32768
    int e = i >> 9;
    int bb = (i >> 6) & 7;
    int d = i & 63;
    Bt[i] = f32_bf16_hw(bases[bb * 4096 + d * 64 + e]);   // Bt[e][b*64+d]
  } else {
    if (tid < 128) zero0[tid] = 0;      // gcur2/gcur region
  }
}

// K1: bucket histograms (LDS atomics only) + x->bf16 cast
__global__ __launch_bounds__(256) void k_count(const int* __restrict__ src,
                                               const int* __restrict__ tgt,
                                               int* __restrict__ H,
                                               const float* __restrict__ x,
                                               uint16_t* __restrict__ xb,
                                               int nE) {
  int b = blockIdx.x;
  int tid = threadIdx.x;
  if (b >= CNT_BLOCKS) {
    int i = (b - CNT_BLOCKS) * 256 + tid;   // exact: i < 1,600,000
    const float* xp = x + (size_t)i * 8;
    float4v q0 = __builtin_nontemporal_load((const float4v*)xp);
    float4v q1 = __builtin_nontemporal_load((const float4v*)(xp + 4));
    short8b o;
    o[0] = f32_bf16_hw(q0[0]); o[1] = f32_bf16_hw(q0[1]); o[2] = f32_bf16_hw(q0[2]); o[3] = f32_bf16_hw(q0[3]);
    o[4] = f32_bf16_hw(q1[0]); o[5] = f32_bf16_hw(q1[1]); o[6] = f32_bf16_hw(q1[2]); o[7] = f32_bf16_hw(q1[3]);
    *(short8b*)(xb + (size_t)i * 8) = o;    // cacheable: phaseAB gathers it
    return;
  }
  __shared__ int bh[NB];
  if (tid < NB) bh[tid] = 0;
  __syncthreads();
#pragma unroll
  for (int k = 0; k < 4; ++k) {
    int i = b * 1024 + k * 256 + tid;
    if (i < nE) {
      atomicAdd(&bh[tgt[i] >> 10], 1);
      atomicAdd(&bh[src[i] >> 10], 1);
    }
  }
  __syncthreads();
  if (tid < NB) H[b * NB + tid] = bh[tid];
}

// K2: per bucket b, scan H[blk][b] over blocks -> baseM[blk][b]
__global__ __launch_bounds__(256) void k_base(const int* __restrict__ H,
                                              int* __restrict__ baseM,
                                              int* __restrict__ regStart,
                                              int* __restrict__ regTot,
                                              int* __restrict__ gcur2) {
  int b = blockIdx.x;
  int tid = threadIdx.x;
  int lane = tid & 63, wid = tid >> 6;
  int vals[4]; int ts = 0;
#pragma unroll
  for (int k = 0; k < 4; ++k) {
    int idx = tid * 4 + k;
    vals[k] = (idx < CNT_BLOCKS) ? H[idx * NB + b] : 0;
    ts += vals[k];
  }
  int incl = ts;
  for (int off = 1; off < 64; off <<= 1) {
    int n = __shfl_up(incl, off, 64);
    if (lane >= off) incl += n;
  }
  __shared__ int wsum[4];
  __shared__ int s_start;
  if (lane == 63) wsum[wid] = incl;
  __syncthreads();
  if (tid == 0) {
    int t0 = wsum[0], t1 = wsum[1], t2 = wsum[2], t3 = wsum[3];
    int tot = t0 + t1 + t2 + t3;
    int st = atomicAdd(gcur2, tot);
    regStart[b] = st;
    regTot[b] = tot;
    s_start = st;
    wsum[0] = 0; wsum[1] = t0; wsum[2] = t0 + t1; wsum[3] = t0 + t1 + t2;
  }
  __syncthreads();
  int run = s_start + wsum[wid] + incl - ts;
#pragma unroll
  for (int k = 0; k < 4; ++k) {
    int idx = tid * 4 + k;
    if (idx < CNT_BLOCKS) {
      baseM[idx * NB + b] = run;
      run += vals[k];
    }
  }
}

// K3: scatter packed endpoint items ((v&1023)<<21 | itemid) into regions
__global__ __launch_bounds__(256) void k_scat(const int* __restrict__ src,
                                              const int* __restrict__ tgt,
                                              const int* __restrict__ baseM,
                                              int* __restrict__ scratch,
                                              int nE) {
  int b = blockIdx.x;
  int tid = threadIdx.x;
  __shared__ int bh[NB];
  __shared__ int bb[NB];
  if (tid < NB) { bh[tid] = 0; bb[tid] = baseM[b * NB + tid]; }
  __syncthreads();
#pragma unroll
  for (int k = 0; k < 4; ++k) {
    int i = b * 1024 + k * 256 + tid;
    if (i < nE) {
      int t_ = tgt[i], s_ = src[i];
      int offT = atomicAdd(&bh[t_ >> 10], 1);
      scratch[bb[t_ >> 10] + offT] = ((t_ & 1023) << 21) | (2 * i);
      int offS = atomicAdd(&bh[s_ >> 10], 1);
      scratch[bb[s_ >> 10] + offS] = ((s_ & 1023) << 21) | (2 * i + 1);
    }
  }
}

// K4: per-bucket slot assignment + segment scan; writes eslot (ABSOLUTE),
// vstart/cntt, and the self-loop rec2=(v, NREL) at the segment end.
__global__ __launch_bounds__(256) void k_slot(const int* __restrict__ scratch,
                                              const int* __restrict__ regStart,
                                              const int* __restrict__ regTot,
                                              const int* __restrict__ mask,
                                              int* __restrict__ eslot,
                                              int* __restrict__ vstart,
                                              int* __restrict__ cntt,
                                              int* __restrict__ gcur,
                                              int2* __restrict__ rec2,
                                              int nN) {
  int b = blockIdx.x;
  int tid = threadIdx.x;
  __shared__ int cnt[1024];
  __shared__ int sabs[1024];
  __shared__ int wsum[4];
  __shared__ int s_base;
#pragma unroll
  for (int k = 0; k < 4; ++k) cnt[tid + k * 256] = 0;
  __syncthreads();
  int start = regStart[b];
  int tot = regTot[b];
  for (int it = tid; it < tot; it += 256)
    atomicAdd(&cnt[scratch[start + it] >> 21], 1);
  __syncthreads();
  int lane = tid & 63, wid = tid >> 6;
  int vals[4]; int ts = 0;
#pragma unroll
  for (int k = 0; k < 4; ++k) {
    int j = tid * 4 + k;
    int v = b * 1024 + j;
    int m = (v < nN) ? (mask[v] ? 1 : 0) : 0;
    vals[k] = cnt[j] + m;
    ts += vals[k];
  }
  int incl = ts;
  for (int off = 1; off < 64; off <<= 1) {
    int n = __shfl_up(incl, off, 64);
    if (lane >= off) incl += n;
  }
  if (lane == 63) wsum[wid] = incl;
  __syncthreads();
  if (tid == 0) {
    int t0 = wsum[0], t1 = wsum[1], t2 = wsum[2], t3 = wsum[3];
    s_base = atomicAdd(gcur, t0 + t1 + t2 + t3);
    wsum[0] = 0; wsum[1] = t0; wsum[2] = t0 + t1; wsum[3] = t0 + t1 + t2;
  }
  __syncthreads();
  int run = s_base + wsum[wid] + incl - ts;
#pragma unroll
  for (int k = 0; k < 4; ++k) {
    int j = tid * 4 + k;
    sabs[j] = run;
    int v = b * 1024 + j;
    if (v < nN) { vstart[v] = run; cntt[v] = vals[k]; }
    run += vals[k];
  }
  __syncthreads();
  for (int it = tid; it < tot; it += 256) {
    int rec = scratch[start + it];
    int slot = atomicAdd(&sabs[rec >> 21], 1);
    eslot[rec & 0x1FFFFF] = slot;
  }
  __syncthreads();                       // sabs = vstart + edge-count
#pragma unroll
  for (int k = 0; k < 4; ++k) {
    int j = tid * 4 + k;
    int v = b * 1024 + j;
    if (v < nN && mask[v])
      rec2[sabs[j]] = make_int2(v, NREL);   // self record, att row NREL
  }
}

// K5: edge records: rec2[slot] = (source-of-message, relation). 8 B each.
__global__ __launch_bounds__(256) void k_write(const int* __restrict__ src,
                                               const int* __restrict__ tgt,
                                               const int* __restrict__ et,
                                               const int* __restrict__ eslot,
                                               int2* __restrict__ rec2,
                                               int nE) {
  int i = blockIdx.x * 256 + threadIdx.x;
  if (i < nE) {
    int r = et[i];
    long long ev = __builtin_nontemporal_load((const long long*)(eslot + 2 * i));
    int s1 = (int)(ev & 0xFFFFFFFFll);        // slot in tgt's segment
    int s2 = (int)(ev >> 32);                 // slot in src's segment
    int s_ = src[i], t_ = tgt[i];
    rec2[s1] = make_int2(s_, r);              // msg s_ -> t_
    rec2[s2] = make_int2(t_, r);              // msg t_ -> s_
  }
}

// Fused phaseAB: one block per 16 targets. 4 waves x 4 targets accumulate
// g[t][k=(b,d)] = Σ att[r][b]*x[s][d] on the VALU (lane = d, 4-way MLP on
// x-gathers), flush bf16 to LDS, then each wave computes one 16-col MFMA
// quadrant of out[16x64] = g[16x512] · Bt[512x64] and stores f32 directly.
__global__ __launch_bounds__(256) void k_phaseAB(const uint16_t* __restrict__ xb,
                                                 const int2* __restrict__ rec2,
                                                 const uint16_t* __restrict__ Bt,
                                                 const float* __restrict__ att,
                                                 const int* __restrict__ vstart,
                                                 const int* __restrict__ cntt,
                                                 float* __restrict__ out) {
  __shared__ __align__(16) uint16_t s_g[16 * 520];   // 520 = 512 + 8 pad
  __shared__ float s_att[(NREL + 1) * NBASES];
  int tid = threadIdx.x;
  if (tid < (NREL + 1) * NBASES) s_att[tid] = att[tid];
  int wv = tid >> 6;
  int lane = tid & 63;                    // = input dim d
  int T0 = blockIdx.x * 16;

  int tb[4], tc[4];
#pragma unroll
  for (int tt = 0; tt < 4; ++tt) {
    int t = T0 + wv * 4 + tt;
    tb[tt] = vstart[t];
    tc[tt] = cntt[t];
  }
  __syncthreads();                        // s_att ready

  float g[4][8] = {};
  int mx = max(max(tc[0], tc[1]), max(tc[2], tc[3]));
  for (int j = 0; j < mx; ++j) {
#pragma unroll
    for (int tt = 0; tt < 4; ++tt) {
      if (j < tc[tt]) {                   // wave-uniform branch
        int2 rc = rec2[tb[tt] + j];       // uniform 8-B record
        float xv = bf2f(xb[(size_t)rc.x * 64 + lane]);
        const float* ar = &s_att[rc.y * 8];
#pragma unroll
        for (int bb = 0; bb < 8; ++bb)
          g[tt][bb] = fmaf(ar[bb], xv, g[tt][bb]);
      }
    }
  }
  // flush: row = target-in-tile, col k = b*64 + d
#pragma unroll
  for (int tt = 0; tt < 4; ++tt) {
    int row = wv * 4 + tt;
#pragma unroll
    for (int bb = 0; bb < 8; ++bb)
      s_g[row * 520 + bb * 64 + lane] = f32_bf16_hw(g[tt][bb]);
  }
  __syncthreads();

  // MFMA: wave wv computes output cols [wv*16, wv*16+16)
  int quad = lane >> 4, m16 = lane & 15;
  float4v acc0 = {0.f, 0.f, 0.f, 0.f}, acc1 = {0.f, 0.f, 0.f, 0.f};
  const uint16_t* bt = Bt + (size_t)(wv * 16 + m16) * 512 + quad * 8;
  const uint16_t* ga = &s_g[m16 * 520 + quad * 8];
#pragma unroll
  for (int kk = 0; kk < 16; kk += 2) {
    short8b a0 = *(const short8b*)(ga + kk * 32);
    short8b b0 = *(const short8b*)(bt + kk * 32);
    acc0 = __builtin_amdgcn_mfma_f32_16x16x32_bf16(a0, b0, acc0, 0, 0, 0);
    short8b a1 = *(const short8b*)(ga + (kk + 1) * 32);
    short8b b1 = *(const short8b*)(bt + (kk + 1) * 32);
    acc1 = __builtin_amdgcn_mfma_f32_16x16x32_bf16(a1, b1, acc1, 0, 0, 0);
  }
  // C/D: row(target) = quad*4+reg, col(dim) = m16  [within this nt quadrant]
#pragma unroll
  for (int reg = 0; reg < 4; ++reg)
    out[(size_t)(T0 + quad * 4 + reg) * 64 + wv * 16 + m16] = acc0[reg] + acc1[reg];
}

// ======================================================================
// FALLBACK PATH (atomic scatter) — used only if ws_size too small
// ======================================================================
#define F_WS_HIST    0
#define F_WS_CURSOR  64
#define F_WS_START   128
#define F_WS_WT      512
#define F_WS_TILEREL 139776
#define F_WS_RECS    262144
#define F_MAXTILES   112520
#define F_MAXRECS    (F_MAXTILES * 16)

__global__ __launch_bounds__(256) void k_wprep(const float* __restrict__ bases,
                                               const float* __restrict__ att,
                                               uint16_t* __restrict__ Wt) {
  int i = blockIdx.x * 256 + threadIdx.x;
  if (i >= 17 * 64 * 64) return;
  int r = i >> 12;
  int e = (i >> 6) & 63;
  int d = i & 63;
  float acc = 0.f;
  for (int b = 0; b < NBASES; ++b)
    acc += att[r * NBASES + b] * bases[b * 4096 + d * 64 + e];
  Wt[i] = (uint16_t)f32_bf16(acc);
}

__global__ __launch_bounds__(256) void f_hist(const int* __restrict__ et,
                                              int* __restrict__ hist, int nE) {
  __shared__ int lh[NREL];
  if (threadIdx.x < NREL) lh[threadIdx.x] = 0;
  __syncthreads();
  int i = blockIdx.x * 256 + threadIdx.x;
  if (i < nE) atomicAdd(&lh[et[i]], 2);
  __syncthreads();
  if (threadIdx.x < NREL && lh[threadIdx.x] > 0)
    atomicAdd(&hist[threadIdx.x], lh[threadIdx.x]);
}

__global__ __launch_bounds__(256) void f_prefix(const int* __restrict__ hist,
                                                int* __restrict__ cursor,
                                                int* __restrict__ start,
                                                uint8_t* __restrict__ tileRel,
                                                int nN, int maxTiles) {
  __shared__ int s_start[17];
  if (threadIdx.x == 0) {
    int base = nN;
    for (int r = 0; r < NREL; ++r) {
      s_start[r] = base;
      cursor[r] = base;
      start[r] = base;
      base = (base + hist[r] + 15) & ~15;
    }
    s_start[16] = base;
    start[16] = base;
  }
  __syncthreads();
  int endp = s_start[16];
  for (int t = threadIdx.x; t < maxTiles; t += 256) {
    int p = t * 16;
    uint8_t r;
    if (p < nN) r = 16;
    else if (p >= endp) r = 255;
    else {
      int q = 0;
      for (int k = 1; k < NREL; ++k) if (p >= s_start[k]) q = k;
      r = (uint8_t)q;
    }
    tileRel[t] = r;
  }
}

__global__ __launch_bounds__(256) void f_scatter(const int* __restrict__ src,
                                                 const int* __restrict__ tgt,
                                                 const int* __restrict__ et,
                                                 const int* __restrict__ mask,
                                                 int2* __restrict__ recs,
                                                 int* __restrict__ cursor,
                                                 int nE, int nN) {
  __shared__ int lh[NREL];
  __shared__ int lbase[NREL];
  if (threadIdx.x < NREL) lh[threadIdx.x] = 0;
  __syncthreads();
  int i = blockIdx.x * 256 + threadIdx.x;
  int r = 0, loff = 0;
  bool isEdge = (i < nE);
  if (isEdge) {
    r = et[i];
    loff = atomicAdd(&lh[r], 2);
  }
  __syncthreads();
  if (threadIdx.x < NREL)
    lbase[threadIdx.x] = (lh[threadIdx.x] > 0) ? atomicAdd(&cursor[threadIdx.x], lh[threadIdx.x]) : 0;
  __syncthreads();
  if (isEdge) {
    int pos = lbase[r] + loff;
    int s = src[i], t = tgt[i];
    *(int4*)(recs + pos) = make_int4(s, t, t, s);
  }
  if (i < nN) {
    recs[i] = (mask[i] != 0) ? make_int2(i, i) : make_int2(-1, -1);
  }
}

__global__ __launch_bounds__(256) void f_compute(const float* __restrict__ x,
                                                 const int2* __restrict__ recs,
                                                 const uint16_t* __restrict__ Wt,
                                                 const uint8_t* __restrict__ tileRel,
                                                 float* __restrict__ out,
                                                 int ntiles) {
  const int lane = threadIdx.x & 63;
  const int quad = lane >> 4;
  const int m16 = lane & 15;
  const int wave = blockIdx.x * 4 + (threadIdx.x >> 6);
  const int t0 = wave * 4;

  int curRel = -1;
  short8b bfrag[4][2] = {};

  for (int it = 0; it < 4; ++it) {
    int t = t0 + it;
    if (t >= ntiles) return;
    int rel = tileRel[t];
    if (rel == 255) return;

    if (rel != curRel) {
      curRel = rel;
      const uint16_t* wbase = Wt + (size_t)rel * 4096;
      for (int nt = 0; nt < 4; ++nt)
        for (int kt = 0; kt < 2; ++kt)
          bfrag[nt][kt] = *(const short8b*)(wbase + (size_t)(nt * 16 + m16) * 64 + kt * 32 + quad * 8);
    }

    int2 rec = recs[t * 16 + m16];
    int u = rec.x < 0 ? 0 : rec.x;

    const float* xp = x + (size_t)u * 64 + quad * 8;
    float4v q0 = *(const float4v*)(xp);
    float4v q1 = *(const float4v*)(xp + 4);
    float4v q2 = *(const float4v*)(xp + 32);
    float4v q3 = *(const float4v*)(xp + 36);
    short8b a0, a1;
    a0[0] = f32_bf16(q0[0]); a0[1] = f32_bf16(q0[1]); a0[2] = f32_bf16(q0[2]); a0[3] = f32_bf16(q0[3]);
    a0[4] = f32_bf16(q1[0]); a0[5] = f32_bf16(q1[1]); a0[6] = f32_bf16(q1[2]); a0[7] = f32_bf16(q1[3]);
    a1[0] = f32_bf16(q2[0]); a1[1] = f32_bf16(q2[1]); a1[2] = f32_bf16(q2[2]); a1[3] = f32_bf16(q2[3]);
    a1[4] = f32_bf16(q3[0]); a1[5] = f32_bf16(q3[1]); a1[6] = f32_bf16(q3[2]); a1[7] = f32_bf16(q3[3]);

    float4v acc[4];
    for (int nt = 0; nt < 4; ++nt) { acc[nt][0] = 0.f; acc[nt][1] = 0.f; acc[nt][2] = 0.f; acc[nt][3] = 0.f; }
    for (int nt = 0; nt < 4; ++nt) {
      acc[nt] = __builtin_amdgcn_mfma_f32_16x16x32_bf16(a0, bfrag[nt][0], acc[nt], 0, 0, 0);
      acc[nt] = __builtin_amdgcn_mfma_f32_16x16x32_bf16(a1, bfrag[nt][1], acc[nt], 0, 0, 0);
    }

    int tg[4];
    for (int reg = 0; reg < 4; ++reg)
      tg[reg] = __shfl(rec.y, quad * 4 + reg, 64);
    for (int reg = 0; reg < 4; ++reg) {
      if (tg[reg] < 0) continue;
      float* op = out + (size_t)tg[reg] * 64 + m16;
      for (int nt = 0; nt < 4; ++nt)
        __hip_atomic_fetch_add(op + nt * 16, acc[nt][reg], __ATOMIC_RELAXED, __HIP_MEMORY_SCOPE_AGENT);
    }
  }
}

// ======================================================================
extern "C" void kernel_launch(void* const* d_in, const int* in_sizes, int n_in,
                              void* d_out, int out_size, void* d_ws, size_t ws_size,
                              hipStream_t stream) {
  const float* x     = (const float*)d_in[0];
  const int*   mask  = (const int*)d_in[1];
  const int*   src   = (const int*)d_in[2];
  const int*   tgt   = (const int*)d_in[3];
  const int*   et    = (const int*)d_in[4];
  const float* bases = (const float*)d_in[5];
  const float* att   = (const float*)d_in[6];
  float* out = (float*)d_out;
  char* ws = (char*)d_ws;

  if (ws_size >= WS_GATE) {
    // ---------- g-formulation path ----------
    int*      gcur2   = (int*)(ws + WS_GCUR2);
    int*      gcur    = (int*)(ws + WS_GCUR);
    uint16_t* Bt      = (uint16_t*)(ws + WS_BT);
    int*      vstart  = (int*)(ws + WS_VSTART);
    int*      cntt    = (int*)(ws + WS_CNTT);
    int*      eslot   = (int*)(ws + WS_ESLOT);
    int*      scratch = (int*)(ws + WS_SCRATCH);
    int*      H       = (int*)(ws + WS_H);
    int*      baseM   = (int*)(ws + WS_BASEM);
    int*      regStart= (int*)(ws + WS_REGS);
    int*      regTot  = regStart + NB;
    int2*     rec2    = (int2*)(ws + WS_REC2);
    uint16_t* xb      = (uint16_t*)(ws + WS_XB);

    k_init<<<129, 256, 0, stream>>>(bases, Bt, (int*)ws);
    k_count<<<CNT_BLOCKS + CAST_BLOCKS, 256, 0, stream>>>(src, tgt, H, x, xb, N_EDGES);
    k_base<<<NB, 256, 0, stream>>>(H, baseM, regStart, regTot, gcur2);
    k_scat<<<CNT_BLOCKS, 256, 0, stream>>>(src, tgt, baseM, scratch, N_EDGES);
    k_slot<<<NB, 256, 0, stream>>>(scratch, regStart, regTot, mask, eslot, vstart, cntt, gcur, rec2, N_NODES);
    k_write<<<(N_EDGES + 255) / 256, 256, 0, stream>>>(src, tgt, et, eslot, rec2, N_EDGES);
    k_phaseAB<<<N_NODES / 16, 256, 0, stream>>>(xb, rec2, Bt, att, vstart, cntt, out);
  } else {
    // ---------- fallback: atomic path ----------
    int*      hist    = (int*)(ws + F_WS_HIST);
    int*      cursor  = (int*)(ws + F_WS_CURSOR);
    int*      start   = (int*)(ws + F_WS_START);
    uint16_t* Wt      = (uint16_t*)(ws + F_WS_WT);
    uint8_t*  tileRel = (uint8_t*)(ws + F_WS_TILEREL);
    int2*     recs    = (int2*)(ws + F_WS_RECS);

    (void)hipMemsetAsync(out, 0, (size_t)N_NODES * 64 * sizeof(float), stream);
    (void)hipMemsetAsync(ws, 0, 512, stream);
    (void)hipMemsetAsync(recs, 0xFF, (size_t)F_MAXRECS * sizeof(int2), stream);

    k_wprep<<<(17 * 64 * 64 + 255) / 256, 256, 0, stream>>>(bases, att, Wt);
    f_hist<<<(N_EDGES + 255) / 256, 256, 0, stream>>>(et, hist, N_EDGES);
    f_prefix<<<1, 256, 0, stream>>>(hist, cursor, start, tileRel, N_NODES, F_MAXTILES);
    f_scatter<<<(N_EDGES + 255) / 256, 256, 0, stream>>>(src, tgt, et, mask, recs, cursor, N_EDGES, N_NODES);
    f_compute<<<(F_MAXTILES + 15) / 16, 256, 0, stream>>>(x, recs, Wt, tileRel, out, F_MAXTILES);
  }
}

// Round 10
// 405.288 us; speedup vs baseline: 1.0940x; 1.0940x over previous
//
#include <hip/hip_runtime.h>
#include <hip/hip_bf16.h>
#include <stdint.h>
#include <stddef.h>

#define N_NODES 200000
#define N_EDGES 800000
#define NREL 16
#define NBASES 8

typedef __attribute__((ext_vector_type(8))) short short8b;
typedef __attribute__((ext_vector_type(4))) float float4v;
typedef __attribute__((ext_vector_type(4))) int int4v;

__device__ __forceinline__ short f32_bf16(float f) {
  uint32_t u = __builtin_bit_cast(uint32_t, f);
  uint32_t r = u + 0x7FFFu + ((u >> 16) & 1u);
  return (short)(uint16_t)(r >> 16);
}
// hardware RNE conversion (gfx950); same rounding as the manual version
__device__ __forceinline__ uint16_t f32_bf16_hw(float f) {
  __hip_bfloat16 h = __float2bfloat16(f);
  return __builtin_bit_cast(uint16_t, h);
}
__device__ __forceinline__ float bf2f(uint16_t h) {
  return __builtin_bit_cast(float, (uint32_t)h << 16);
}

// ======================================================================
// MAIN PATH (v10): g-formulation, NO message materialization.
//   out[t] = (Σ_{e->t} att[r_e]⊗x_{s_e}) · Bstack   (K=512 MFMA)
// v10 fix over v9: k_phaseAB inner loop is branchless (zero att row for
// padded iterations) and software-pipelined (records prefetched one
// iteration ahead) -> 8 independent loads in flight per wave instead of a
// branch-serialized 1 (v9's 272 us was this latency chain).
// ======================================================================
#define NB 196                 // node buckets of 1024 (196*1024 >= 200000)
#define CNT_BLOCKS  782        // ceil(800000/1024) edge blocks
#define CAST_BLOCKS 6250
#define MAXSLOTS (2 * N_EDGES + N_NODES)   // 1.8M

// workspace layout (all offsets 16-B aligned where needed)
#define WS_GCUR2   128        // 1 int (bucket-region allocator)
#define WS_GCUR    384        // 1 int (segment allocator)
#define WS_BT      512        // 64*512 u16 = 65536 -> ends 66048
#define WS_VSTART  66560      // 200000 int
#define WS_CNTT    866560     // 200000 int
#define WS_ESLOT   1666560    // 2E int = 6.4 MB
#define WS_SCRATCH 8066560    // 2E int = 6.4 MB
#define WS_H       14466560   // 782*196 int
#define WS_BASEM   15079648   // 782*196 int
#define WS_REGS    15692736   // 2*196 int
#define WS_REC2    15694336   // MAXSLOTS int2 = 14.4 MB
#define WS_XB      30094336   // 200000*64 u16 = 25.6 MB -> ends 55.7 MB
// gate: keep the old (round-8) threshold, known to pass on this harness
#define WS_GATE    (17056128 + (size_t)112528 * 16 * 128)

// Fused: Bt prep (blocks 0..127) | zero control head (block 128)
__global__ __launch_bounds__(256) void k_init(const float* __restrict__ bases,
                                              uint16_t* __restrict__ Bt,
                                              int* __restrict__ zero0) {
  int b = blockIdx.x;
  int tid = threadIdx.x;
  if (b < 128) {
    int i = b * 256 + tid;              // i < 32768
    int e = i >> 9;
    int bb = (i >> 6) & 7;
    int d = i & 63;
    Bt[i] = f32_bf16_hw(bases[bb * 4096 + d * 64 + e]);   // Bt[e][b*64+d]
  } else {
    if (tid < 128) zero0[tid] = 0;      // gcur2/gcur region
  }
}

// K1: bucket histograms (LDS atomics only) + x->bf16 cast
__global__ __launch_bounds__(256) void k_count(const int* __restrict__ src,
                                               const int* __restrict__ tgt,
                                               int* __restrict__ H,
                                               const float* __restrict__ x,
                                               uint16_t* __restrict__ xb,
                                               int nE) {
  int b = blockIdx.x;
  int tid = threadIdx.x;
  if (b >= CNT_BLOCKS) {
    int i = (b - CNT_BLOCKS) * 256 + tid;   // exact: i < 1,600,000
    const float* xp = x + (size_t)i * 8;
    float4v q0 = __builtin_nontemporal_load((const float4v*)xp);
    float4v q1 = __builtin_nontemporal_load((const float4v*)(xp + 4));
    short8b o;
    o[0] = f32_bf16_hw(q0[0]); o[1] = f32_bf16_hw(q0[1]); o[2] = f32_bf16_hw(q0[2]); o[3] = f32_bf16_hw(q0[3]);
    o[4] = f32_bf16_hw(q1[0]); o[5] = f32_bf16_hw(q1[1]); o[6] = f32_bf16_hw(q1[2]); o[7] = f32_bf16_hw(q1[3]);
    *(short8b*)(xb + (size_t)i * 8) = o;    // cacheable: phaseAB gathers it
    return;
  }
  __shared__ int bh[NB];
  if (tid < NB) bh[tid] = 0;
  __syncthreads();
#pragma unroll
  for (int k = 0; k < 4; ++k) {
    int i = b * 1024 + k * 256 + tid;
    if (i < nE) {
      atomicAdd(&bh[tgt[i] >> 10], 1);
      atomicAdd(&bh[src[i] >> 10], 1);
    }
  }
  __syncthreads();
  if (tid < NB) H[b * NB + tid] = bh[tid];
}

// K2: per bucket b, scan H[blk][b] over blocks -> baseM[blk][b]
__global__ __launch_bounds__(256) void k_base(const int* __restrict__ H,
                                              int* __restrict__ baseM,
                                              int* __restrict__ regStart,
                                              int* __restrict__ regTot,
                                              int* __restrict__ gcur2) {
  int b = blockIdx.x;
  int tid = threadIdx.x;
  int lane = tid & 63, wid = tid >> 6;
  int vals[4]; int ts = 0;
#pragma unroll
  for (int k = 0; k < 4; ++k) {
    int idx = tid * 4 + k;
    vals[k] = (idx < CNT_BLOCKS) ? H[idx * NB + b] : 0;
    ts += vals[k];
  }
  int incl = ts;
  for (int off = 1; off < 64; off <<= 1) {
    int n = __shfl_up(incl, off, 64);
    if (lane >= off) incl += n;
  }
  __shared__ int wsum[4];
  __shared__ int s_start;
  if (lane == 63) wsum[wid] = incl;
  __syncthreads();
  if (tid == 0) {
    int t0 = wsum[0], t1 = wsum[1], t2 = wsum[2], t3 = wsum[3];
    int tot = t0 + t1 + t2 + t3;
    int st = atomicAdd(gcur2, tot);
    regStart[b] = st;
    regTot[b] = tot;
    s_start = st;
    wsum[0] = 0; wsum[1] = t0; wsum[2] = t0 + t1; wsum[3] = t0 + t1 + t2;
  }
  __syncthreads();
  int run = s_start + wsum[wid] + incl - ts;
#pragma unroll
  for (int k = 0; k < 4; ++k) {
    int idx = tid * 4 + k;
    if (idx < CNT_BLOCKS) {
      baseM[idx * NB + b] = run;
      run += vals[k];
    }
  }
}

// K3: scatter packed endpoint items ((v&1023)<<21 | itemid) into regions
__global__ __launch_bounds__(256) void k_scat(const int* __restrict__ src,
                                              const int* __restrict__ tgt,
                                              const int* __restrict__ baseM,
                                              int* __restrict__ scratch,
                                              int nE) {
  int b = blockIdx.x;
  int tid = threadIdx.x;
  __shared__ int bh[NB];
  __shared__ int bb[NB];
  if (tid < NB) { bh[tid] = 0; bb[tid] = baseM[b * NB + tid]; }
  __syncthreads();
#pragma unroll
  for (int k = 0; k < 4; ++k) {
    int i = b * 1024 + k * 256 + tid;
    if (i < nE) {
      int t_ = tgt[i], s_ = src[i];
      int offT = atomicAdd(&bh[t_ >> 10], 1);
      scratch[bb[t_ >> 10] + offT] = ((t_ & 1023) << 21) | (2 * i);
      int offS = atomicAdd(&bh[s_ >> 10], 1);
      scratch[bb[s_ >> 10] + offS] = ((s_ & 1023) << 21) | (2 * i + 1);
    }
  }
}

// K4: per-bucket slot assignment + segment scan; writes eslot (ABSOLUTE),
// vstart/cntt, and the self-loop rec2=(v, NREL) at the segment end.
__global__ __launch_bounds__(256) void k_slot(const int* __restrict__ scratch,
                                              const int* __restrict__ regStart,
                                              const int* __restrict__ regTot,
                                              const int* __restrict__ mask,
                                              int* __restrict__ eslot,
                                              int* __restrict__ vstart,
                                              int* __restrict__ cntt,
                                              int* __restrict__ gcur,
                                              int2* __restrict__ rec2,
                                              int nN) {
  int b = blockIdx.x;
  int tid = threadIdx.x;
  __shared__ int cnt[1024];
  __shared__ int sabs[1024];
  __shared__ int wsum[4];
  __shared__ int s_base;
#pragma unroll
  for (int k = 0; k < 4; ++k) cnt[tid + k * 256] = 0;
  __syncthreads();
  int start = regStart[b];
  int tot = regTot[b];
  for (int it = tid; it < tot; it += 256)
    atomicAdd(&cnt[scratch[start + it] >> 21], 1);
  __syncthreads();
  int lane = tid & 63, wid = tid >> 6;
  int vals[4]; int ts = 0;
#pragma unroll
  for (int k = 0; k < 4; ++k) {
    int j = tid * 4 + k;
    int v = b * 1024 + j;
    int m = (v < nN) ? (mask[v] ? 1 : 0) : 0;
    vals[k] = cnt[j] + m;
    ts += vals[k];
  }
  int incl = ts;
  for (int off = 1; off < 64; off <<= 1) {
    int n = __shfl_up(incl, off, 64);
    if (lane >= off) incl += n;
  }
  if (lane == 63) wsum[wid] = incl;
  __syncthreads();
  if (tid == 0) {
    int t0 = wsum[0], t1 = wsum[1], t2 = wsum[2], t3 = wsum[3];
    s_base = atomicAdd(gcur, t0 + t1 + t2 + t3);
    wsum[0] = 0; wsum[1] = t0; wsum[2] = t0 + t1; wsum[3] = t0 + t1 + t2;
  }
  __syncthreads();
  int run = s_base + wsum[wid] + incl - ts;
#pragma unroll
  for (int k = 0; k < 4; ++k) {
    int j = tid * 4 + k;
    sabs[j] = run;
    int v = b * 1024 + j;
    if (v < nN) { vstart[v] = run; cntt[v] = vals[k]; }
    run += vals[k];
  }
  __syncthreads();
  for (int it = tid; it < tot; it += 256) {
    int rec = scratch[start + it];
    int slot = atomicAdd(&sabs[rec >> 21], 1);
    eslot[rec & 0x1FFFFF] = slot;
  }
  __syncthreads();                       // sabs = vstart + edge-count
#pragma unroll
  for (int k = 0; k < 4; ++k) {
    int j = tid * 4 + k;
    int v = b * 1024 + j;
    if (v < nN && mask[v])
      rec2[sabs[j]] = make_int2(v, NREL);   // self record, att row NREL
  }
}

// K5: edge records: rec2[slot] = (source-of-message, relation). 8 B each.
__global__ __launch_bounds__(256) void k_write(const int* __restrict__ src,
                                               const int* __restrict__ tgt,
                                               const int* __restrict__ et,
                                               const int* __restrict__ eslot,
                                               int2* __restrict__ rec2,
                                               int nE) {
  int i = blockIdx.x * 256 + threadIdx.x;
  if (i < nE) {
    int r = et[i];
    long long ev = __builtin_nontemporal_load((const long long*)(eslot + 2 * i));
    int s1 = (int)(ev & 0xFFFFFFFFll);        // slot in tgt's segment
    int s2 = (int)(ev >> 32);                 // slot in src's segment
    int s_ = src[i], t_ = tgt[i];
    rec2[s1] = make_int2(s_, r);              // msg s_ -> t_
    rec2[s2] = make_int2(t_, r);              // msg t_ -> s_
  }
}

// Fused phaseAB (v10): one block per 16 targets, 4 waves x 4 targets,
// lane = input dim. BRANCHLESS inner loop: padded iterations (j >= cnt)
// read a clamped record and multiply by the ZERO att row (row 17).
// SOFTWARE-PIPELINED: next iteration's 4 rec2 loads are issued alongside
// the current 4 xb gathers -> 8 independent loads in flight per wave.
__global__ __launch_bounds__(256) void k_phaseAB(const uint16_t* __restrict__ xb,
                                                 const int2* __restrict__ rec2,
                                                 const uint16_t* __restrict__ Bt,
                                                 const float* __restrict__ att,
                                                 const int* __restrict__ vstart,
                                                 const int* __restrict__ cntt,
                                                 float* __restrict__ out) {
  __shared__ __align__(16) uint16_t s_g[16 * 520];   // 520 = 512 + 8 pad
  __shared__ float s_att[(NREL + 2) * NBASES];       // row NREL+1 = zeros
  const int ZROW = NREL + 1;
  int tid = threadIdx.x;
  if (tid < (NREL + 1) * NBASES) s_att[tid] = att[tid];
  else if (tid < (NREL + 2) * NBASES) s_att[tid] = 0.f;
  int wv = tid >> 6;
  int lane = tid & 63;                    // = input dim d
  int T0 = blockIdx.x * 16;

  int tb[4], tc[4];
#pragma unroll
  for (int tt = 0; tt < 4; ++tt) {
    int t = T0 + wv * 4 + tt;
    tb[tt] = vstart[t];
    tc[tt] = cntt[t];
  }
  __syncthreads();                        // s_att ready

  float g[4][8] = {};
  int mx = max(max(tc[0], tc[1]), max(tc[2], tc[3]));

  // prologue: fetch records for j=0 (clamped; safe — all rec2 slots are
  // initialized and tb < MAXSLOTS whenever any segment is non-empty)
  int rx[4], ry[4];
#pragma unroll
  for (int tt = 0; tt < 4; ++tt) {
    int2 rc = rec2[tb[tt]];
    rx[tt] = rc.x;
    ry[tt] = (tc[tt] > 0) ? rc.y : ZROW;
  }
  for (int j = 0; j < mx; ++j) {
    // current xb gathers (4 independent 128-B wave loads)
    float xv[4];
#pragma unroll
    for (int tt = 0; tt < 4; ++tt)
      xv[tt] = bf2f(xb[(size_t)rx[tt] * 64 + lane]);
    // prefetch next records (4 independent wave-uniform 8-B loads)
    int nrx[4], nry[4];
#pragma unroll
    for (int tt = 0; tt < 4; ++tt) {
      int jn = j + 1;
      int idx = jn < tc[tt] ? jn : (tc[tt] > 0 ? tc[tt] - 1 : 0);
      int2 rc = rec2[tb[tt] + idx];
      nrx[tt] = rc.x;
      nry[tt] = (jn < tc[tt]) ? rc.y : ZROW;
    }
    // FMA (only waits on the xb batch; rec2 prefetches stay in flight)
#pragma unroll
    for (int tt = 0; tt < 4; ++tt) {
      const float* ar = &s_att[ry[tt] * 8];
#pragma unroll
      for (int bb = 0; bb < 8; ++bb)
        g[tt][bb] = fmaf(ar[bb], xv[tt], g[tt][bb]);
    }
#pragma unroll
    for (int tt = 0; tt < 4; ++tt) { rx[tt] = nrx[tt]; ry[tt] = nry[tt]; }
  }

  // flush: row = target-in-tile, col k = b*64 + d
#pragma unroll
  for (int tt = 0; tt < 4; ++tt) {
    int row = wv * 4 + tt;
#pragma unroll
    for (int bb = 0; bb < 8; ++bb)
      s_g[row * 520 + bb * 64 + lane] = f32_bf16_hw(g[tt][bb]);
  }
  __syncthreads();

  // MFMA: wave wv computes output cols [wv*16, wv*16+16)
  int quad = lane >> 4, m16 = lane & 15;
  float4v acc0 = {0.f, 0.f, 0.f, 0.f}, acc1 = {0.f, 0.f, 0.f, 0.f};
  const uint16_t* bt = Bt + (size_t)(wv * 16 + m16) * 512 + quad * 8;
  const uint16_t* ga = &s_g[m16 * 520 + quad * 8];
#pragma unroll
  for (int kk = 0; kk < 16; kk += 2) {
    short8b a0 = *(const short8b*)(ga + kk * 32);
    short8b b0 = *(const short8b*)(bt + kk * 32);
    acc0 = __builtin_amdgcn_mfma_f32_16x16x32_bf16(a0, b0, acc0, 0, 0, 0);
    short8b a1 = *(const short8b*)(ga + (kk + 1) * 32);
    short8b b1 = *(const short8b*)(bt + (kk + 1) * 32);
    acc1 = __builtin_amdgcn_mfma_f32_16x16x32_bf16(a1, b1, acc1, 0, 0, 0);
  }
  // C/D: row(target) = quad*4+reg, col(dim) = m16  [within this nt quadrant]
#pragma unroll
  for (int reg = 0; reg < 4; ++reg)
    out[(size_t)(T0 + quad * 4 + reg) * 64 + wv * 16 + m16] = acc0[reg] + acc1[reg];
}

// ======================================================================
// FALLBACK PATH (atomic scatter) — used only if ws_size too small
// ======================================================================
#define F_WS_HIST    0
#define F_WS_CURSOR  64
#define F_WS_START   128
#define F_WS_WT      512
#define F_WS_TILEREL 139776
#define F_WS_RECS    262144
#define F_MAXTILES   112520
#define F_MAXRECS    (F_MAXTILES * 16)

__global__ __launch_bounds__(256) void k_wprep(const float* __restrict__ bases,
                                               const float* __restrict__ att,
                                               uint16_t* __restrict__ Wt) {
  int i = blockIdx.x * 256 + threadIdx.x;
  if (i >= 17 * 64 * 64) return;
  int r = i >> 12;
  int e = (i >> 6) & 63;
  int d = i & 63;
  float acc = 0.f;
  for (int b = 0; b < NBASES; ++b)
    acc += att[r * NBASES + b] * bases[b * 4096 + d * 64 + e];
  Wt[i] = (uint16_t)f32_bf16(acc);
}

__global__ __launch_bounds__(256) void f_hist(const int* __restrict__ et,
                                              int* __restrict__ hist, int nE) {
  __shared__ int lh[NREL];
  if (threadIdx.x < NREL) lh[threadIdx.x] = 0;
  __syncthreads();
  int i = blockIdx.x * 256 + threadIdx.x;
  if (i < nE) atomicAdd(&lh[et[i]], 2);
  __syncthreads();
  if (threadIdx.x < NREL && lh[threadIdx.x] > 0)
    atomicAdd(&hist[threadIdx.x], lh[threadIdx.x]);
}

__global__ __launch_bounds__(256) void f_prefix(const int* __restrict__ hist,
                                                int* __restrict__ cursor,
                                                int* __restrict__ start,
                                                uint8_t* __restrict__ tileRel,
                                                int nN, int maxTiles) {
  __shared__ int s_start[17];
  if (threadIdx.x == 0) {
    int base = nN;
    for (int r = 0; r < NREL; ++r) {
      s_start[r] = base;
      cursor[r] = base;
      start[r] = base;
      base = (base + hist[r] + 15) & ~15;
    }
    s_start[16] = base;
    start[16] = base;
  }
  __syncthreads();
  int endp = s_start[16];
  for (int t = threadIdx.x; t < maxTiles; t += 256) {
    int p = t * 16;
    uint8_t r;
    if (p < nN) r = 16;
    else if (p >= endp) r = 255;
    else {
      int q = 0;
      for (int k = 1; k < NREL; ++k) if (p >= s_start[k]) q = k;
      r = (uint8_t)q;
    }
    tileRel[t] = r;
  }
}

__global__ __launch_bounds__(256) void f_scatter(const int* __restrict__ src,
                                                 const int* __restrict__ tgt,
                                                 const int* __restrict__ et,
                                                 const int* __restrict__ mask,
                                                 int2* __restrict__ recs,
                                                 int* __restrict__ cursor,
                                                 int nE, int nN) {
  __shared__ int lh[NREL];
  __shared__ int lbase[NREL];
  if (threadIdx.x < NREL) lh[threadIdx.x] = 0;
  __syncthreads();
  int i = blockIdx.x * 256 + threadIdx.x;
  int r = 0, loff = 0;
  bool isEdge = (i < nE);
  if (isEdge) {
    r = et[i];
    loff = atomicAdd(&lh[r], 2);
  }
  __syncthreads();
  if (threadIdx.x < NREL)
    lbase[threadIdx.x] = (lh[threadIdx.x] > 0) ? atomicAdd(&cursor[threadIdx.x], lh[threadIdx.x]) : 0;
  __syncthreads();
  if (isEdge) {
    int pos = lbase[r] + loff;
    int s = src[i], t = tgt[i];
    *(int4*)(recs + pos) = make_int4(s, t, t, s);
  }
  if (i < nN) {
    recs[i] = (mask[i] != 0) ? make_int2(i, i) : make_int2(-1, -1);
  }
}

__global__ __launch_bounds__(256) void f_compute(const float* __restrict__ x,
                                                 const int2* __restrict__ recs,
                                                 const uint16_t* __restrict__ Wt,
                                                 const uint8_t* __restrict__ tileRel,
                                                 float* __restrict__ out,
                                                 int ntiles) {
  const int lane = threadIdx.x & 63;
  const int quad = lane >> 4;
  const int m16 = lane & 15;
  const int wave = blockIdx.x * 4 + (threadIdx.x >> 6);
  const int t0 = wave * 4;

  int curRel = -1;
  short8b bfrag[4][2] = {};

  for (int it = 0; it < 4; ++it) {
    int t = t0 + it;
    if (t >= ntiles) return;
    int rel = tileRel[t];
    if (rel == 255) return;

    if (rel != curRel) {
      curRel = rel;
      const uint16_t* wbase = Wt + (size_t)rel * 4096;
      for (int nt = 0; nt < 4; ++nt)
        for (int kt = 0; kt < 2; ++kt)
          bfrag[nt][kt] = *(const short8b*)(wbase + (size_t)(nt * 16 + m16) * 64 + kt * 32 + quad * 8);
    }

    int2 rec = recs[t * 16 + m16];
    int u = rec.x < 0 ? 0 : rec.x;

    const float* xp = x + (size_t)u * 64 + quad * 8;
    float4v q0 = *(const float4v*)(xp);
    float4v q1 = *(const float4v*)(xp + 4);
    float4v q2 = *(const float4v*)(xp + 32);
    float4v q3 = *(const float4v*)(xp + 36);
    short8b a0, a1;
    a0[0] = f32_bf16(q0[0]); a0[1] = f32_bf16(q0[1]); a0[2] = f32_bf16(q0[2]); a0[3] = f32_bf16(q0[3]);
    a0[4] = f32_bf16(q1[0]); a0[5] = f32_bf16(q1[1]); a0[6] = f32_bf16(q1[2]); a0[7] = f32_bf16(q1[3]);
    a1[0] = f32_bf16(q2[0]); a1[1] = f32_bf16(q2[1]); a1[2] = f32_bf16(q2[2]); a1[3] = f32_bf16(q2[3]);
    a1[4] = f32_bf16(q3[0]); a1[5] = f32_bf16(q3[1]); a1[6] = f32_bf16(q3[2]); a1[7] = f32_bf16(q3[3]);

    float4v acc[4];
    for (int nt = 0; nt < 4; ++nt) { acc[nt][0] = 0.f; acc[nt][1] = 0.f; acc[nt][2] = 0.f; acc[nt][3] = 0.f; }
    for (int nt = 0; nt < 4; ++nt) {
      acc[nt] = __builtin_amdgcn_mfma_f32_16x16x32_bf16(a0, bfrag[nt][0], acc[nt], 0, 0, 0);
      acc[nt] = __builtin_amdgcn_mfma_f32_16x16x32_bf16(a1, bfrag[nt][1], acc[nt], 0, 0, 0);
    }

    int tg[4];
    for (int reg = 0; reg < 4; ++reg)
      tg[reg] = __shfl(rec.y, quad * 4 + reg, 64);
    for (int reg = 0; reg < 4; ++reg) {
      if (tg[reg] < 0) continue;
      float* op = out + (size_t)tg[reg] * 64 + m16;
      for (int nt = 0; nt < 4; ++nt)
        __hip_atomic_fetch_add(op + nt * 16, acc[nt][reg], __ATOMIC_RELAXED, __HIP_MEMORY_SCOPE_AGENT);
    }
  }
}

// ======================================================================
extern "C" void kernel_launch(void* const* d_in, const int* in_sizes, int n_in,
                              void* d_out, int out_size, void* d_ws, size_t ws_size,
                              hipStream_t stream) {
  const float* x     = (const float*)d_in[0];
  const int*   mask  = (const int*)d_in[1];
  const int*   src   = (const int*)d_in[2];
  const int*   tgt   = (const int*)d_in[3];
  const int*   et    = (const int*)d_in[4];
  const float* bases = (const float*)d_in[5];
  const float* att   = (const float*)d_in[6];
  float* out = (float*)d_out;
  char* ws = (char*)d_ws;

  if (ws_size >= WS_GATE) {
    // ---------- g-formulation path ----------
    int*      gcur2   = (int*)(ws + WS_GCUR2);
    int*      gcur    = (int*)(ws + WS_GCUR);
    uint16_t* Bt      = (uint16_t*)(ws + WS_BT);
    int*      vstart  = (int*)(ws + WS_VSTART);
    int*      cntt    = (int*)(ws + WS_CNTT);
    int*      eslot   = (int*)(ws + WS_ESLOT);
    int*      scratch = (int*)(ws + WS_SCRATCH);
    int*      H       = (int*)(ws + WS_H);
    int*      baseM   = (int*)(ws + WS_BASEM);
    int*      regStart= (int*)(ws + WS_REGS);
    int*      regTot  = regStart + NB;
    int2*     rec2    = (int2*)(ws + WS_REC2);
    uint16_t* xb      = (uint16_t*)(ws + WS_XB);

    k_init<<<129, 256, 0, stream>>>(bases, Bt, (int*)ws);
    k_count<<<CNT_BLOCKS + CAST_BLOCKS, 256, 0, stream>>>(src, tgt, H, x, xb, N_EDGES);
    k_base<<<NB, 256, 0, stream>>>(H, baseM, regStart, regTot, gcur2);
    k_scat<<<CNT_BLOCKS, 256, 0, stream>>>(src, tgt, baseM, scratch, N_EDGES);
    k_slot<<<NB, 256, 0, stream>>>(scratch, regStart, regTot, mask, eslot, vstart, cntt, gcur, rec2, N_NODES);
    k_write<<<(N_EDGES + 255) / 256, 256, 0, stream>>>(src, tgt, et, eslot, rec2, N_EDGES);
    k_phaseAB<<<N_NODES / 16, 256, 0, stream>>>(xb, rec2, Bt, att, vstart, cntt, out);
  } else {
    // ---------- fallback: atomic path ----------
    int*      hist    = (int*)(ws + F_WS_HIST);
    int*      cursor  = (int*)(ws + F_WS_CURSOR);
    int*      start   = (int*)(ws + F_WS_START);
    uint16_t* Wt      = (uint16_t*)(ws + F_WS_WT);
    uint8_t*  tileRel = (uint8_t*)(ws + F_WS_TILEREL);
    int2*     recs    = (int2*)(ws + F_WS_RECS);

    (void)hipMemsetAsync(out, 0, (size_t)N_NODES * 64 * sizeof(float), stream);
    (void)hipMemsetAsync(ws, 0, 512, stream);
    (void)hipMemsetAsync(recs, 0xFF, (size_t)F_MAXRECS * sizeof(int2), stream);

    k_wprep<<<(17 * 64 * 64 + 255) / 256, 256, 0, stream>>>(bases, att, Wt);
    f_hist<<<(N_EDGES + 255) / 256, 256, 0, stream>>>(et, hist, N_EDGES);
    f_prefix<<<1, 256, 0, stream>>>(hist, cursor, start, tileRel, N_NODES, F_MAXTILES);
    f_scatter<<<(N_EDGES + 255) / 256, 256, 0, stream>>>(src, tgt, et, mask, recs, cursor, N_EDGES, N_NODES);
    f_compute<<<(F_MAXTILES + 15) / 16, 256, 0, stream>>>(x, recs, Wt, tileRel, out, F_MAXTILES);
  }
}